// Round 1
// baseline (301.128 us; speedup 1.0000x reference)
//
#include <hip/hip_runtime.h>
#include <math.h>

#define B_    4096
#define DIN   640
#define DD    128
#define PP    12
#define INV_T 0.25f

typedef __bf16 bft;
typedef __attribute__((ext_vector_type(8))) __bf16 bf16x8;
typedef __attribute__((ext_vector_type(4))) float fx4;

// async 16B global -> LDS (DMA, vmcnt-tracked, no VGPR round trip)
__device__ __forceinline__ void gload16(const float* gp, float* lp) {
  __builtin_amdgcn_global_load_lds(
      (const __attribute__((address_space(1))) unsigned int*)gp,
      (__attribute__((address_space(3))) unsigned int*)lp,
      16, 0, 0);
}

// ---------------------------------------------------------------------------
// prep: split weights into bf16 hi/lo (a = hi + lo, hi = RN_bf16(a)).
// ---------------------------------------------------------------------------
__global__ __launch_bounds__(256) void prep_kernel(
    const float* __restrict__ gw1, const float* __restrict__ pw1,
    const float* __restrict__ gw2, const float* __restrict__ pw2,
    bft* __restrict__ w1hg, bft* __restrict__ w1lg,
    bft* __restrict__ w1hp, bft* __restrict__ w1lp,
    bft* __restrict__ w2hg, bft* __restrict__ w2lg,
    bft* __restrict__ w2hp, bft* __restrict__ w2lp)
{
  int idx = blockIdx.x * 256 + threadIdx.x;   // 0 .. 196607
  const float* src; bft *dh, *dl; int off;
  if (idx < 81920)       { src = gw1; dh = w1hg; dl = w1lg; off = idx; }
  else if (idx < 163840) { src = pw1; dh = w1hp; dl = w1lp; off = idx - 81920; }
  else if (idx < 180224) { src = gw2; dh = w2hg; dl = w2lg; off = idx - 163840; }
  else                   { src = pw2; dh = w2hp; dl = w2lp; off = idx - 180224; }
  float x = src[off];
  bft h = (bft)x;
  dh[off] = h;
  dl[off] = (bft)(x - (float)h);
}

// ---------------------------------------------------------------------------
// MFMA embed (split-bf16): Y = normalize(relu(X@W1^T+b1)@W2^T+b2).
// R8: BM=64 tile (was 128). LDS 32 KB -> __launch_bounds__(256,4) gives
// 4 blocks/CU (16 waves/CU, was 8); grid 832 blocks => ALL blocks resident,
// no dispatch imbalance. 4 independent per-CU blocks at staggered loop
// phases cover each other's per-chunk DMA-drain stalls (R7 was
// in-flight-bytes/Little's-law bound at 1.36 TB/s demand BW).
// X staged via async global_load_lds, double-buffered 64x32 fp32 tiles,
// XOR-swizzled slots (slot = kq ^ (row&7)) on the GLOBAL side so staging
// stays lane-contiguous and ds_read_b128 phases hit all 32 banks.
// xbuf (2x8 KB) aliases the h region; LDS = 32 KB.
// Grid: blocks 0..63 = g-stream, 64..831 = p-stream.
// ---------------------------------------------------------------------------
__global__ __launch_bounds__(256, 4) void embed_kernel(
    const float* __restrict__ ebg, const float* __restrict__ ebp,
    const bft* __restrict__ w1hg, const bft* __restrict__ w1lg, const float* __restrict__ b1g,
    const bft* __restrict__ w2hg, const bft* __restrict__ w2lg, const float* __restrict__ b2g,
    const bft* __restrict__ w1hp, const bft* __restrict__ w1lp, const float* __restrict__ b1p,
    const bft* __restrict__ w2hp, const bft* __restrict__ w2lp, const float* __restrict__ b2p,
    float* __restrict__ outg, float* __restrict__ outp)
{
  __shared__ bft hsm[2 * 64 * 128];           // 32768 B
  float* xb0 = (float*)hsm;                   // [64][32] fp32, 8 KB (aliases h)
  float* xb1 = xb0 + 2048;                    // second buffer, 8 KB
  bft* hhi = hsm;
  bft* hlo = hsm + 64 * 128;
  float* halfsq = (float*)hsm;                // aliased after h dead

  const int t = threadIdx.x;
  const int w = t >> 6, lane = t & 63;
  const int wm = w >> 1, wn = w & 1;
  const int ln = lane & 15, quad = lane >> 4;

  const float *X, *B1, *B2;
  const bft *W1H, *W1L, *W2H, *W2L;
  float* Y;
  long m0;
  if (blockIdx.x < 64) {
    X = ebg; W1H = w1hg; W1L = w1lg; B1 = b1g; W2H = w2hg; W2L = w2lg; B2 = b2g;
    Y = outg; m0 = (long)blockIdx.x * 64;
  } else {
    X = ebp; W1H = w1hp; W1L = w1lp; B1 = b1p; W2H = w2hp; W2L = w2lp; B2 = b2p;
    Y = outp; m0 = (long)(blockIdx.x - 64) * 64;
  }

  // staging coords: wave w fills rows w*16..w*16+15; 2 instrs of 64 lanes.
  // lane -> row_local = j*8 + (lane>>3), slot = lane&7, global kq = slot^(row&7)
  const int srow = lane >> 3;                       // 0..7
  const int skq  = (lane & 7) ^ srow;               // swizzled k-quad
  const float* xsrc = X + (size_t)(m0 + w * 16 + srow) * DIN + skq * 4;
  // LDS dest fp32 index for (wave w, instr j): (w*16 + j*8)*32 + lane*4
  const int ldst = w * 16 * 32 + lane * 4;

#define GLX(bufp, k0)                                        \
  _Pragma("unroll")                                          \
  for (int j = 0; j < 2; j++)                                \
    gload16(xsrc + (size_t)j * 8 * DIN + (k0), (bufp) + ldst + j * 8 * 32);

  // MFMA A-fragment read coords: m = wm*32+mt*16+ln, slots s0,s0^1
  const int s0 = ((quad << 1) ^ (ln & 7));

  const bft *p1h[4], *p1l[4];
#pragma unroll
  for (int nt = 0; nt < 4; nt++) {
    int n = wn * 64 + nt * 16 + ln;
    p1h[nt] = W1H + (size_t)n * DIN + quad * 8;
    p1l[nt] = W1L + (size_t)n * DIN + quad * 8;
  }

  fx4 acc[2][4];
#pragma unroll
  for (int mt = 0; mt < 2; mt++)
#pragma unroll
    for (int nt = 0; nt < 4; nt++) acc[mt][nt] = (fx4){0.f, 0.f, 0.f, 0.f};

#define LOADW(wh, wl, koff)                                \
  _Pragma("unroll")                                        \
  for (int nt = 0; nt < 4; nt++) {                         \
    wh[nt] = *(const bf16x8*)(p1h[nt] + (koff));           \
    wl[nt] = *(const bf16x8*)(p1l[nt] + (koff));           \
  }

#define PH1CHUNK(bufp, wh, wl)                                                         \
  {                                                                                    \
    bf16x8 ah[2], al[2];                                                               \
    _Pragma("unroll")                                                                  \
    for (int mt = 0; mt < 2; mt++) {                                                   \
      const float* rp = (bufp) + (wm * 32 + mt * 16 + ln) * 32;                        \
      fx4 x0 = *(const fx4*)(rp + s0 * 4);                                             \
      fx4 x1 = *(const fx4*)(rp + (s0 ^ 1) * 4);                                       \
      _Pragma("unroll")                                                                \
      for (int j = 0; j < 4; j++) {                                                    \
        float xv = x0[j];                                                              \
        bft hh = (bft)xv;                                                              \
        ah[mt][j] = hh;                                                                \
        al[mt][j] = (bft)(xv - (float)hh);                                             \
        float yv = x1[j];                                                              \
        bft hh2 = (bft)yv;                                                             \
        ah[mt][4 + j] = hh2;                                                           \
        al[mt][4 + j] = (bft)(yv - (float)hh2);                                        \
      }                                                                                \
    }                                                                                  \
    _Pragma("unroll")                                                                  \
    for (int mt = 0; mt < 2; mt++)                                                     \
      _Pragma("unroll")                                                                \
      for (int nt = 0; nt < 4; nt++) {                                                 \
        acc[mt][nt] = __builtin_amdgcn_mfma_f32_16x16x32_bf16(ah[mt], wh[nt], acc[mt][nt], 0, 0, 0); \
        acc[mt][nt] = __builtin_amdgcn_mfma_f32_16x16x32_bf16(al[mt], wh[nt], acc[mt][nt], 0, 0, 0); \
        acc[mt][nt] = __builtin_amdgcn_mfma_f32_16x16x32_bf16(ah[mt], wl[nt], acc[mt][nt], 0, 0, 0); \
      }                                                                                \
  }

  // ---- phase 1: async-staged K loop, unrolled x2 (static W reg buffers) ----
  bf16x8 wha[4], wla[4], whb[4], wlb[4];
  GLX(xb0, 0)
  LOADW(wha, wla, 0)
  __syncthreads();                       // drain chunk 0 DMA
  for (int kc = 0; kc < 20; kc += 2) {
    const int k0 = kc * 32;
    GLX(xb1, k0 + 32)                    // chunk kc+1 (always <= 19)
    LOADW(whb, wlb, k0 + 32)
    PH1CHUNK(xb0, wha, wla)
    __syncthreads();                     // drain kc+1 DMA; xb0 free
    if (kc < 18) {
      GLX(xb0, k0 + 64)
      LOADW(wha, wla, k0 + 64)
    }
    PH1CHUNK(xb1, whb, wlb)
    __syncthreads();                     // drain kc+2 DMA; xb1 free
  }

  // ---- bias1 + relu, split h into LDS (XOR-swizzled 16B chunks) ----
  // (loop's final barrier: all xbuf reads done; safe to overwrite via h)
#pragma unroll
  for (int nt = 0; nt < 4; nt++) {
    float bv = B1[wn * 64 + nt * 16 + ln];
    int c8 = wn * 8 + nt * 2 + (ln >> 3);
    int c7 = ln & 7;
#pragma unroll
    for (int mt = 0; mt < 2; mt++) {
#pragma unroll
      for (int r = 0; r < 4; r++) {
        float v = fmaxf(acc[mt][nt][r] + bv, 0.f);
        bft h = (bft)v;
        bft l = (bft)(v - (float)h);
        int m = wm * 32 + mt * 16 + quad * 4 + r;
        int addr = m * 128 + ((c8 ^ (m & 15)) << 3) + c7;
        hhi[addr] = h;
        hlo[addr] = l;
      }
    }
  }

  // ---- phase 2: acc2 = h @ W2^T + b2 (split-bf16), W2 pipelined ----
  const bft *p2h[4], *p2l[4];
#pragma unroll
  for (int nt = 0; nt < 4; nt++) {
    int n = wn * 64 + nt * 16 + ln;
    p2h[nt] = W2H + (size_t)n * DD + quad * 8;
    p2l[nt] = W2L + (size_t)n * DD + quad * 8;
  }
  fx4 acc2[2][4];
#pragma unroll
  for (int nt = 0; nt < 4; nt++) {
    float bv = B2[wn * 64 + nt * 16 + ln];
#pragma unroll
    for (int mt = 0; mt < 2; mt++) acc2[mt][nt] = (fx4){bv, bv, bv, bv};
  }

#define LOADW2(wh, wl, koff)                               \
  _Pragma("unroll")                                        \
  for (int nt = 0; nt < 4; nt++) {                         \
    wh[nt] = *(const bf16x8*)(p2h[nt] + (koff));           \
    wl[nt] = *(const bf16x8*)(p2l[nt] + (koff));           \
  }

#define PH2CHUNK(kcv, wh, wl)                                                          \
  {                                                                                    \
    bf16x8 ah2[2], al2[2];                                                             \
    _Pragma("unroll")                                                                  \
    for (int mt = 0; mt < 2; mt++) {                                                   \
      int m = wm * 32 + mt * 16 + ln;                                                  \
      int c8 = ((kcv) * 4 + quad) ^ (m & 15);                                          \
      ah2[mt] = *(const bf16x8*)&hhi[m * 128 + (c8 << 3)];                             \
      al2[mt] = *(const bf16x8*)&hlo[m * 128 + (c8 << 3)];                             \
    }                                                                                  \
    _Pragma("unroll")                                                                  \
    for (int mt = 0; mt < 2; mt++)                                                     \
      _Pragma("unroll")                                                                \
      for (int nt = 0; nt < 4; nt++) {                                                 \
        acc2[mt][nt] = __builtin_amdgcn_mfma_f32_16x16x32_bf16(ah2[mt], wh[nt], acc2[mt][nt], 0, 0, 0); \
        acc2[mt][nt] = __builtin_amdgcn_mfma_f32_16x16x32_bf16(al2[mt], wh[nt], acc2[mt][nt], 0, 0, 0); \
        acc2[mt][nt] = __builtin_amdgcn_mfma_f32_16x16x32_bf16(ah2[mt], wl[nt], acc2[mt][nt], 0, 0, 0); \
      }                                                                                \
  }

  bf16x8 q2ha[4], q2la[4], q2hb[4], q2lb[4];
  LOADW2(q2ha, q2la, 0)        // issued pre-barrier: barrier hides the latency
  __syncthreads();
  LOADW2(q2hb, q2lb, 32)
  PH2CHUNK(0, q2ha, q2la)
  LOADW2(q2ha, q2la, 64)
  PH2CHUNK(1, q2hb, q2lb)
  LOADW2(q2hb, q2lb, 96)
  PH2CHUNK(2, q2ha, q2la)
  PH2CHUNK(3, q2hb, q2lb)
  __syncthreads();   // h reads done; halfsq may overwrite hsm

  // ---- row L2 normalize ----
#pragma unroll
  for (int mt = 0; mt < 2; mt++) {
#pragma unroll
    for (int r = 0; r < 4; r++) {
      float s = 0.f;
#pragma unroll
      for (int nt = 0; nt < 4; nt++) { float v = acc2[mt][nt][r]; s += v * v; }
      s += __shfl_xor(s, 1, 64);
      s += __shfl_xor(s, 2, 64);
      s += __shfl_xor(s, 4, 64);
      s += __shfl_xor(s, 8, 64);
      if (ln == 0) halfsq[(wm * 32 + mt * 16 + quad * 4 + r) * 2 + wn] = s;
    }
  }
  __syncthreads();
#pragma unroll
  for (int mt = 0; mt < 2; mt++) {
#pragma unroll
    for (int r = 0; r < 4; r++) {
      int row = wm * 32 + mt * 16 + quad * 4 + r;
      float rinv = 1.0f / sqrtf(halfsq[row * 2] + halfsq[row * 2 + 1]);
#pragma unroll
      for (int nt = 0; nt < 4; nt++)
        Y[(m0 + row) * DD + wn * 64 + nt * 16 + ln] = acc2[mt][nt][r] * rinv;
    }
  }
}

// ---------------------------------------------------------------------------
// Symmetric KL of one D=128 row pair per 64-lane wave; inputs pre-scaled 1/T.
// sym = sum_i (pu_i - pv_i)*(au_i - av_i)  (LSE terms cancel exactly).
// No max-subtraction: args bounded (|a|<=0.25 dil, [0,1] dcl) -> exp safe.
// ---------------------------------------------------------------------------
__device__ __forceinline__ float sym_kl_row(float au0, float au1, float av0, float av1)
{
  float eu0 = __expf(au0), eu1 = __expf(au1);
  float ev0 = __expf(av0), ev1 = __expf(av1);
  float su = eu0 + eu1, sv = ev0 + ev1;
#pragma unroll
  for (int o = 32; o > 0; o >>= 1) {
    su += __shfl_xor(su, o, 64);
    sv += __shfl_xor(sv, o, 64);
  }
  float ru = 1.0f / su, rv = 1.0f / sv;
  float d0 = au0 - av0, d1 = au1 - av1;
  float part = (eu0 * ru - ev0 * rv) * d0 + (eu1 * ru - ev1 * rv) * d1;
#pragma unroll
  for (int o = 32; o > 0; o >>= 1) part += __shfl_xor(part, o, 64);
  return part;
}

// ---------------------------------------------------------------------------
// Fused loss: one wave per b. Holds p[0..11][b] in regs (float2/lane), computes
// pbar, dil, and all 12 dcl terms in ONE pass over p.
// ---------------------------------------------------------------------------
__global__ __launch_bounds__(256) void loss_kernel(
    const float* __restrict__ g, const float* __restrict__ p,
    float* __restrict__ pdil, float* __restrict__ pdcl)
{
  __shared__ float wd[4], wc[4];
  int w = threadIdx.x >> 6, lane = threadIdx.x & 63;
  int b = blockIdx.x * 4 + w;
  float2 pl[PP];
  float sx = 0.f, sy = 0.f;
#pragma unroll
  for (int l = 0; l < PP; l++) {
    pl[l] = *(const float2*)&p[((size_t)l * B_ + b) * DD + lane * 2];
    sx += pl[l].x; sy += pl[l].y;
  }
  sx *= (1.0f / PP); sy *= (1.0f / PP);
  float2 gv = *(const float2*)&g[(size_t)b * DD + lane * 2];

  float dil = sym_kl_row(gv.x * INV_T, gv.y * INV_T, sx * INV_T, sy * INV_T) * 0.125f;

  float dcl = 0.f;
#pragma unroll
  for (int l = 0; l < PP; l++) {
    float u0 = (gv.x - pl[l].x) * (gv.x - pl[l].x) * INV_T;
    float u1 = (gv.y - pl[l].y) * (gv.y - pl[l].y) * INV_T;
    float v0 = (sx - pl[l].x) * (sx - pl[l].x) * INV_T;
    float v1 = (sy - pl[l].y) * (sy - pl[l].y) * INV_T;
    dcl += sym_kl_row(u0, u1, v0, v1);
  }
  dcl *= (1.0f / 96.0f);

  if (lane == 0) { wd[w] = dil; wc[w] = dcl; }
  __syncthreads();
  if (threadIdx.x == 0) pdil[blockIdx.x] = wd[0] + wd[1] + wd[2] + wd[3];
  if (threadIdx.x == 1) pdcl[blockIdx.x] = wc[0] + wc[1] + wc[2] + wc[3];
}

__global__ __launch_bounds__(256) void final_kernel(const float* __restrict__ pdil,
                                                    const float* __restrict__ pdcl,
                                                    float* __restrict__ out)
{
  __shared__ float red[8];
  int t = threadIdx.x;
  float s0 = 0.f, s1 = 0.f;
  for (int i = t; i < 1024; i += 256) { s0 += pdil[i]; s1 += pdcl[i]; }
#pragma unroll
  for (int o = 32; o > 0; o >>= 1) {
    s0 += __shfl_xor(s0, o, 64);
    s1 += __shfl_xor(s1, o, 64);
  }
  int wid = t >> 6, lane = t & 63;
  if (lane == 0) { red[wid] = s0; red[4 + wid] = s1; }
  __syncthreads();
  if (t == 0) out[0] = red[0] + red[1] + red[2] + red[3];
  if (t == 1) out[1] = red[4] + red[5] + red[6] + red[7];
}

extern "C" void kernel_launch(void* const* d_in, const int* in_sizes, int n_in,
                              void* d_out, int out_size, void* d_ws, size_t ws_size,
                              hipStream_t stream)
{
  const float* ebg = (const float*)d_in[0];
  const float* ebp = (const float*)d_in[1];
  const float* gw1 = (const float*)d_in[3];
  const float* gb1 = (const float*)d_in[4];
  const float* gw2 = (const float*)d_in[5];
  const float* gb2 = (const float*)d_in[6];
  const float* pw1 = (const float*)d_in[7];
  const float* pb1 = (const float*)d_in[8];
  const float* pw2 = (const float*)d_in[9];
  const float* pb2 = (const float*)d_in[10];
  float* out = (float*)d_out;

  float* ws   = (float*)d_ws;
  float* g    = ws;                           // 524288 f
  float* p    = g + (size_t)B_ * DD;          // 6291456 f
  float* pdil = p + (size_t)PP * B_ * DD;     // 1024 f
  float* pdcl = pdil + 1024;                  // 1024 f
  bft* wb     = (bft*)(pdcl + 1024);
  bft* w1hg = wb;                 bft* w1lg = w1hg + 81920;
  bft* w1hp = w1lg + 81920;       bft* w1lp = w1hp + 81920;
  bft* w2hg = w1lp + 81920;       bft* w2lg = w2hg + 16384;
  bft* w2hp = w2lg + 16384;       bft* w2lp = w2hp + 16384;

  prep_kernel<<<768, 256, 0, stream>>>(gw1, pw1, gw2, pw2,
                                       w1hg, w1lg, w1hp, w1lp,
                                       w2hg, w2lg, w2hp, w2lp);
  embed_kernel<<<832, 256, 0, stream>>>(ebg, ebp,
                                        w1hg, w1lg, gb1, w2hg, w2lg, gb2,
                                        w1hp, w1lp, pb1, w2hp, w2lp, pb2,
                                        g, p);
  loss_kernel<<<B_ / 4, 256, 0, stream>>>(g, p, pdil, pdcl);
  final_kernel<<<1, 256, 0, stream>>>(pdil, pdcl, out);
}

// Round 3
// 265.088 us; speedup vs baseline: 1.1360x; 1.1360x over previous
//
#include <hip/hip_runtime.h>
#include <math.h>

#define B_    4096
#define DIN   640
#define DD    128
#define PP    12
#define INV_T 0.25f

typedef __bf16 bft;
typedef __attribute__((ext_vector_type(8))) __bf16 bf16x8;
typedef __attribute__((ext_vector_type(4))) float fx4;

// async 16B global -> LDS (DMA, vmcnt-tracked, no VGPR round trip)
__device__ __forceinline__ void gload16(const float* gp, float* lp) {
  __builtin_amdgcn_global_load_lds(
      (const __attribute__((address_space(1))) unsigned int*)gp,
      (__attribute__((address_space(3))) unsigned int*)lp,
      16, 0, 0);
}

// ---------------------------------------------------------------------------
// prep: split weights into bf16 hi/lo (a = hi + lo, hi = RN_bf16(a)).
// ---------------------------------------------------------------------------
__global__ __launch_bounds__(256) void prep_kernel(
    const float* __restrict__ gw1, const float* __restrict__ pw1,
    const float* __restrict__ gw2, const float* __restrict__ pw2,
    bft* __restrict__ w1hg, bft* __restrict__ w1lg,
    bft* __restrict__ w1hp, bft* __restrict__ w1lp,
    bft* __restrict__ w2hg, bft* __restrict__ w2lg,
    bft* __restrict__ w2hp, bft* __restrict__ w2lp)
{
  int idx = blockIdx.x * 256 + threadIdx.x;   // 0 .. 196607
  const float* src; bft *dh, *dl; int off;
  if (idx < 81920)       { src = gw1; dh = w1hg; dl = w1lg; off = idx; }
  else if (idx < 163840) { src = pw1; dh = w1hp; dl = w1lp; off = idx - 81920; }
  else if (idx < 180224) { src = gw2; dh = w2hg; dl = w2lg; off = idx - 163840; }
  else                   { src = pw2; dh = w2hp; dl = w2lp; off = idx - 180224; }
  float x = src[off];
  bft h = (bft)x;
  dh[off] = h;
  dl[off] = (bft)(x - (float)h);
}

// ---------------------------------------------------------------------------
// MFMA embed (split-bf16): Y = normalize(relu(X@W1^T+b1)@W2^T+b2).
// R10 == R9 resubmit (R9 bench was an infra flake: container failed with no
// pytest output; kernel re-audited — barrier counts uniform, vmcnt arithmetic
// and slot lifecycle verified, no hang path).
// BM=128 (R8's BM=64 regressed: 2x barrier events, 2x W re-reads). R7/R8
// limiter was per-chunk __syncthreads() == s_waitcnt vmcnt(0): drains the
// SAME chunk's DMA -> every chunk pays full load latency un-overlapped.
// Fix = T4 counted vmcnt: 4-deep X buffers (4x16KB, same 64KB aliasing h),
// raw s_barrier + s_waitcnt vmcnt(32) (24 for chunk 0) -> chunk k's wait
// lands 3 chunk-periods after issue; 2-3 chunks in flight across barriers.
// Tail chunks issue dummy loads (chunk-0 addrs, free slots) to keep the
// vmcnt count a compile-time constant. Full drain after the loop before
// h overwrites the x-buffers.
// Slot lifecycle: compute(c) reads slot c&3 after {per-wave vmcnt -> barrier}
// (all waves' GLX(c) complete); GLX(c+3) targets slot (c-1)&3, issued after
// barrier(c) => all waves drained their slot-(c-1) ds_reads (lgkmcnt(0)
// before barrier).
// Grid: blocks 0..31 = g-stream, 32..415 = p-stream.
// ---------------------------------------------------------------------------
__global__ __launch_bounds__(256, 2) void embed_kernel(
    const float* __restrict__ ebg, const float* __restrict__ ebp,
    const bft* __restrict__ w1hg, const bft* __restrict__ w1lg, const float* __restrict__ b1g,
    const bft* __restrict__ w2hg, const bft* __restrict__ w2lg, const float* __restrict__ b2g,
    const bft* __restrict__ w1hp, const bft* __restrict__ w1lp, const float* __restrict__ b1p,
    const bft* __restrict__ w2hp, const bft* __restrict__ w2lp, const float* __restrict__ b2p,
    float* __restrict__ outg, float* __restrict__ outp)
{
  __shared__ bft hsm[2 * 128 * 128];          // 65536 B
  float* xbase = (float*)hsm;                 // 4 slots x [128][32] fp32 (16 KB each)
  bft* hhi = hsm;
  bft* hlo = hsm + 128 * 128;
  float* halfsq = (float*)hsm;                // aliased after h dead

  const int t = threadIdx.x;
  const int w = t >> 6, lane = t & 63;
  const int wm = w >> 1, wn = w & 1;
  const int ln = lane & 15, quad = lane >> 4;

  const float *X, *B1, *B2;
  const bft *W1H, *W1L, *W2H, *W2L;
  float* Y;
  long m0;
  if (blockIdx.x < 32) {
    X = ebg; W1H = w1hg; W1L = w1lg; B1 = b1g; W2H = w2hg; W2L = w2lg; B2 = b2g;
    Y = outg; m0 = (long)blockIdx.x * 128;
  } else {
    X = ebp; W1H = w1hp; W1L = w1lp; B1 = b1p; W2H = w2hp; W2L = w2lp; B2 = b2p;
    Y = outp; m0 = (long)(blockIdx.x - 32) * 128;
  }

  // staging coords: wave w fills rows w*32..w*32+31; 4 instrs of 64 lanes.
  // lane -> row_local = j*8 + (lane>>3), slot = lane&7, global kq = slot^(row&7)
  const int srow = lane >> 3;                       // 0..7
  const int skq  = (lane & 7) ^ srow;               // swizzled k-quad
  const float* xsrc = X + (size_t)(m0 + w * 32 + srow) * DIN + skq * 4;
  // LDS dest fp32 index for (wave w, instr j): (w*32 + j*8)*32 + lane*4
  const int ldst = w * 32 * 32 + lane * 4;

#define GLX(bufp, k0)                                        \
  _Pragma("unroll")                                          \
  for (int j = 0; j < 4; j++)                                \
    gload16(xsrc + (size_t)j * 8 * DIN + (k0), (bufp) + ldst + j * 8 * 32);

  // MFMA A-fragment read coords: m = wm*64+mt*16+ln, slots s0,s0^1
  const int s0 = ((quad << 1) ^ (ln & 7));

  const bft *p1h[4], *p1l[4];
#pragma unroll
  for (int nt = 0; nt < 4; nt++) {
    int n = wn * 64 + nt * 16 + ln;
    p1h[nt] = W1H + (size_t)n * DIN + quad * 8;
    p1l[nt] = W1L + (size_t)n * DIN + quad * 8;
  }

  fx4 acc[4][4];
#pragma unroll
  for (int mt = 0; mt < 4; mt++)
#pragma unroll
    for (int nt = 0; nt < 4; nt++) acc[mt][nt] = (fx4){0.f, 0.f, 0.f, 0.f};

#define LOADW(wh, wl, koff)                                \
  _Pragma("unroll")                                        \
  for (int nt = 0; nt < 4; nt++) {                         \
    wh[nt] = *(const bf16x8*)(p1h[nt] + (koff));           \
    wl[nt] = *(const bf16x8*)(p1l[nt] + (koff));           \
  }

#define PH1CHUNK(bufp, wh, wl)                                                         \
  {                                                                                    \
    bf16x8 ah[4], al[4];                                                               \
    _Pragma("unroll")                                                                  \
    for (int mt = 0; mt < 4; mt++) {                                                   \
      const float* rp = (bufp) + (wm * 64 + mt * 16 + ln) * 32;                        \
      fx4 x0 = *(const fx4*)(rp + s0 * 4);                                             \
      fx4 x1 = *(const fx4*)(rp + (s0 ^ 1) * 4);                                       \
      _Pragma("unroll")                                                                \
      for (int j = 0; j < 4; j++) {                                                    \
        float xv = x0[j];                                                              \
        bft hh = (bft)xv;                                                              \
        ah[mt][j] = hh;                                                                \
        al[mt][j] = (bft)(xv - (float)hh);                                             \
        float yv = x1[j];                                                              \
        bft hh2 = (bft)yv;                                                             \
        ah[mt][4 + j] = hh2;                                                           \
        al[mt][4 + j] = (bft)(yv - (float)hh2);                                        \
      }                                                                                \
    }                                                                                  \
    _Pragma("unroll")                                                                  \
    for (int mt = 0; mt < 4; mt++)                                                     \
      _Pragma("unroll")                                                                \
      for (int nt = 0; nt < 4; nt++) {                                                 \
        acc[mt][nt] = __builtin_amdgcn_mfma_f32_16x16x32_bf16(ah[mt], wh[nt], acc[mt][nt], 0, 0, 0); \
        acc[mt][nt] = __builtin_amdgcn_mfma_f32_16x16x32_bf16(al[mt], wh[nt], acc[mt][nt], 0, 0, 0); \
        acc[mt][nt] = __builtin_amdgcn_mfma_f32_16x16x32_bf16(ah[mt], wl[nt], acc[mt][nt], 0, 0, 0); \
      }                                                                                \
  }

  // ---- phase 1: counted-vmcnt pipelined K loop (20 chunks, 4 LDS slots) ----
  // Per half-step (chunk c): LOADW(c+1) [8 vmem], s_waitcnt vmcnt(N)+lgkmcnt(0),
  // s_barrier, GLX(c+3) [4 vmem] into slot (c+3)&3, compute slot c&3.
  // Steady state: exactly 32 vmem issued after GLX(c) => vmcnt(32) proves
  // GLX(c) complete while keeping GLX(c+2)/GLX(c+3) in flight. Chunk 0 has
  // only 24 issued-after => vmcnt(24). Tail keeps counts constant via dummy
  // loads of chunk-0 data into the (provably free) slot.
  bf16x8 wha[4], wla[4], whb[4], wlb[4];
  GLX(xbase, 0)                       // chunk 0 -> slot 0
  GLX(xbase + 4096, 32)               // chunk 1 -> slot 1
  GLX(xbase + 8192, 64)               // chunk 2 -> slot 2
  LOADW(wha, wla, 0)

#define HALFSTEP(c, WCH, WCL, WNH, WNL, VMTOK)                              \
  {                                                                          \
    const int kn_ = ((c) + 1 < 20) ? ((c) + 1) * 32 : 0;                     \
    LOADW(WNH, WNL, kn_)                                                     \
    asm volatile("s_waitcnt vmcnt(" VMTOK ") lgkmcnt(0)" ::: "memory");      \
    __builtin_amdgcn_s_barrier();                                            \
    __builtin_amdgcn_sched_barrier(0);                                       \
    const int kp_ = ((c) + 3 < 20) ? ((c) + 3) * 32 : 0;                     \
    float* pslot_ = xbase + ((((c) + 3) & 3) << 12);                         \
    GLX(pslot_, kp_)                                                         \
    PH1CHUNK(xbase + ((((c) & 3)) << 12), WCH, WCL)                          \
  }

  HALFSTEP(0, wha, wla, whb, wlb, "24")
  for (int kc = 1; kc < 19; kc += 2) {
    HALFSTEP(kc,     whb, wlb, wha, wla, "32")
    HALFSTEP(kc + 1, wha, wla, whb, wlb, "32")
  }
  HALFSTEP(19, whb, wlb, wha, wla, "32")

  __syncthreads();   // full drain (incl. tail dummy DMAs) before h overwrites xbuf

  // ---- bias1 + relu, split h into LDS (XOR-swizzled 16B chunks) ----
#pragma unroll
  for (int nt = 0; nt < 4; nt++) {
    float bv = B1[wn * 64 + nt * 16 + ln];
    int c8 = wn * 8 + nt * 2 + (ln >> 3);
    int c7 = ln & 7;
#pragma unroll
    for (int mt = 0; mt < 4; mt++) {
#pragma unroll
      for (int r = 0; r < 4; r++) {
        float v = fmaxf(acc[mt][nt][r] + bv, 0.f);
        bft h = (bft)v;
        bft l = (bft)(v - (float)h);
        int m = wm * 64 + mt * 16 + quad * 4 + r;
        int addr = m * 128 + ((c8 ^ (m & 15)) << 3) + c7;
        hhi[addr] = h;
        hlo[addr] = l;
      }
    }
  }

  // ---- phase 2: acc2 = h @ W2^T + b2 (split-bf16), W2 pipelined ----
  const bft *p2h[4], *p2l[4];
#pragma unroll
  for (int nt = 0; nt < 4; nt++) {
    int n = wn * 64 + nt * 16 + ln;
    p2h[nt] = W2H + (size_t)n * DD + quad * 8;
    p2l[nt] = W2L + (size_t)n * DD + quad * 8;
  }
  fx4 acc2[4][4];
#pragma unroll
  for (int nt = 0; nt < 4; nt++) {
    float bv = B2[wn * 64 + nt * 16 + ln];
#pragma unroll
    for (int mt = 0; mt < 4; mt++) acc2[mt][nt] = (fx4){bv, bv, bv, bv};
  }

#define LOADW2(wh, wl, koff)                               \
  _Pragma("unroll")                                        \
  for (int nt = 0; nt < 4; nt++) {                         \
    wh[nt] = *(const bf16x8*)(p2h[nt] + (koff));           \
    wl[nt] = *(const bf16x8*)(p2l[nt] + (koff));           \
  }

#define PH2CHUNK(kcv, wh, wl)                                                          \
  {                                                                                    \
    bf16x8 ah2[4], al2[4];                                                             \
    _Pragma("unroll")                                                                  \
    for (int mt = 0; mt < 4; mt++) {                                                   \
      int m = wm * 64 + mt * 16 + ln;                                                  \
      int c8 = ((kcv) * 4 + quad) ^ (m & 15);                                          \
      ah2[mt] = *(const bf16x8*)&hhi[m * 128 + (c8 << 3)];                             \
      al2[mt] = *(const bf16x8*)&hlo[m * 128 + (c8 << 3)];                             \
    }                                                                                  \
    _Pragma("unroll")                                                                  \
    for (int mt = 0; mt < 4; mt++)                                                     \
      _Pragma("unroll")                                                                \
      for (int nt = 0; nt < 4; nt++) {                                                 \
        acc2[mt][nt] = __builtin_amdgcn_mfma_f32_16x16x32_bf16(ah2[mt], wh[nt], acc2[mt][nt], 0, 0, 0); \
        acc2[mt][nt] = __builtin_amdgcn_mfma_f32_16x16x32_bf16(al2[mt], wh[nt], acc2[mt][nt], 0, 0, 0); \
        acc2[mt][nt] = __builtin_amdgcn_mfma_f32_16x16x32_bf16(ah2[mt], wl[nt], acc2[mt][nt], 0, 0, 0); \
      }                                                                                \
  }

  bf16x8 q2ha[4], q2la[4], q2hb[4], q2lb[4];
  LOADW2(q2ha, q2la, 0)        // issued pre-barrier: barrier hides the latency
  __syncthreads();
  LOADW2(q2hb, q2lb, 32)
  PH2CHUNK(0, q2ha, q2la)
  LOADW2(q2ha, q2la, 64)
  PH2CHUNK(1, q2hb, q2lb)
  LOADW2(q2hb, q2lb, 96)
  PH2CHUNK(2, q2ha, q2la)
  PH2CHUNK(3, q2hb, q2lb)
  __syncthreads();   // h reads done; halfsq may overwrite hsm

  // ---- row L2 normalize ----
#pragma unroll
  for (int mt = 0; mt < 4; mt++) {
#pragma unroll
    for (int r = 0; r < 4; r++) {
      float s = 0.f;
#pragma unroll
      for (int nt = 0; nt < 4; nt++) { float v = acc2[mt][nt][r]; s += v * v; }
      s += __shfl_xor(s, 1, 64);
      s += __shfl_xor(s, 2, 64);
      s += __shfl_xor(s, 4, 64);
      s += __shfl_xor(s, 8, 64);
      if (ln == 0) halfsq[(wm * 64 + mt * 16 + quad * 4 + r) * 2 + wn] = s;
    }
  }
  __syncthreads();
#pragma unroll
  for (int mt = 0; mt < 4; mt++) {
#pragma unroll
    for (int r = 0; r < 4; r++) {
      int row = wm * 64 + mt * 16 + quad * 4 + r;
      float rinv = 1.0f / sqrtf(halfsq[row * 2] + halfsq[row * 2 + 1]);
#pragma unroll
      for (int nt = 0; nt < 4; nt++)
        Y[(m0 + row) * DD + wn * 64 + nt * 16 + ln] = acc2[mt][nt][r] * rinv;
    }
  }
}

// ---------------------------------------------------------------------------
// Symmetric KL of one D=128 row pair per 64-lane wave; inputs pre-scaled 1/T.
// sym = sum_i (pu_i - pv_i)*(au_i - av_i)  (LSE terms cancel exactly).
// No max-subtraction: args bounded (|a|<=0.25 dil, [0,1] dcl) -> exp safe.
// ---------------------------------------------------------------------------
__device__ __forceinline__ float sym_kl_row(float au0, float au1, float av0, float av1)
{
  float eu0 = __expf(au0), eu1 = __expf(au1);
  float ev0 = __expf(av0), ev1 = __expf(av1);
  float su = eu0 + eu1, sv = ev0 + ev1;
#pragma unroll
  for (int o = 32; o > 0; o >>= 1) {
    su += __shfl_xor(su, o, 64);
    sv += __shfl_xor(sv, o, 64);
  }
  float ru = 1.0f / su, rv = 1.0f / sv;
  float d0 = au0 - av0, d1 = au1 - av1;
  float part = (eu0 * ru - ev0 * rv) * d0 + (eu1 * ru - ev1 * rv) * d1;
#pragma unroll
  for (int o = 32; o > 0; o >>= 1) part += __shfl_xor(part, o, 64);
  return part;
}

// ---------------------------------------------------------------------------
// Fused loss: one wave per b. Holds p[0..11][b] in regs (float2/lane), computes
// pbar, dil, and all 12 dcl terms in ONE pass over p.
// ---------------------------------------------------------------------------
__global__ __launch_bounds__(256) void loss_kernel(
    const float* __restrict__ g, const float* __restrict__ p,
    float* __restrict__ pdil, float* __restrict__ pdcl)
{
  __shared__ float wd[4], wc[4];
  int w = threadIdx.x >> 6, lane = threadIdx.x & 63;
  int b = blockIdx.x * 4 + w;
  float2 pl[PP];
  float sx = 0.f, sy = 0.f;
#pragma unroll
  for (int l = 0; l < PP; l++) {
    pl[l] = *(const float2*)&p[((size_t)l * B_ + b) * DD + lane * 2];
    sx += pl[l].x; sy += pl[l].y;
  }
  sx *= (1.0f / PP); sy *= (1.0f / PP);
  float2 gv = *(const float2*)&g[(size_t)b * DD + lane * 2];

  float dil = sym_kl_row(gv.x * INV_T, gv.y * INV_T, sx * INV_T, sy * INV_T) * 0.125f;

  float dcl = 0.f;
#pragma unroll
  for (int l = 0; l < PP; l++) {
    float u0 = (gv.x - pl[l].x) * (gv.x - pl[l].x) * INV_T;
    float u1 = (gv.y - pl[l].y) * (gv.y - pl[l].y) * INV_T;
    float v0 = (sx - pl[l].x) * (sx - pl[l].x) * INV_T;
    float v1 = (sy - pl[l].y) * (sy - pl[l].y) * INV_T;
    dcl += sym_kl_row(u0, u1, v0, v1);
  }
  dcl *= (1.0f / 96.0f);

  if (lane == 0) { wd[w] = dil; wc[w] = dcl; }
  __syncthreads();
  if (threadIdx.x == 0) pdil[blockIdx.x] = wd[0] + wd[1] + wd[2] + wd[3];
  if (threadIdx.x == 1) pdcl[blockIdx.x] = wc[0] + wc[1] + wc[2] + wc[3];
}

__global__ __launch_bounds__(256) void final_kernel(const float* __restrict__ pdil,
                                                    const float* __restrict__ pdcl,
                                                    float* __restrict__ out)
{
  __shared__ float red[8];
  int t = threadIdx.x;
  float s0 = 0.f, s1 = 0.f;
  for (int i = t; i < 1024; i += 256) { s0 += pdil[i]; s1 += pdcl[i]; }
#pragma unroll
  for (int o = 32; o > 0; o >>= 1) {
    s0 += __shfl_xor(s0, o, 64);
    s1 += __shfl_xor(s1, o, 64);
  }
  int wid = t >> 6, lane = t & 63;
  if (lane == 0) { red[wid] = s0; red[4 + wid] = s1; }
  __syncthreads();
  if (t == 0) out[0] = red[0] + red[1] + red[2] + red[3];
  if (t == 1) out[1] = red[4] + red[5] + red[6] + red[7];
}

extern "C" void kernel_launch(void* const* d_in, const int* in_sizes, int n_in,
                              void* d_out, int out_size, void* d_ws, size_t ws_size,
                              hipStream_t stream)
{
  const float* ebg = (const float*)d_in[0];
  const float* ebp = (const float*)d_in[1];
  const float* gw1 = (const float*)d_in[3];
  const float* gb1 = (const float*)d_in[4];
  const float* gw2 = (const float*)d_in[5];
  const float* gb2 = (const float*)d_in[6];
  const float* pw1 = (const float*)d_in[7];
  const float* pb1 = (const float*)d_in[8];
  const float* pw2 = (const float*)d_in[9];
  const float* pb2 = (const float*)d_in[10];
  float* out = (float*)d_out;

  float* ws   = (float*)d_ws;
  float* g    = ws;                           // 524288 f
  float* p    = g + (size_t)B_ * DD;          // 6291456 f
  float* pdil = p + (size_t)PP * B_ * DD;     // 1024 f
  float* pdcl = pdil + 1024;                  // 1024 f
  bft* wb     = (bft*)(pdcl + 1024);
  bft* w1hg = wb;                 bft* w1lg = w1hg + 81920;
  bft* w1hp = w1lg + 81920;       bft* w1lp = w1hp + 81920;
  bft* w2hg = w1lp + 81920;       bft* w2lg = w2hg + 16384;
  bft* w2hp = w2lg + 16384;       bft* w2lp = w2hp + 16384;

  prep_kernel<<<768, 256, 0, stream>>>(gw1, pw1, gw2, pw2,
                                       w1hg, w1lg, w1hp, w1lp,
                                       w2hg, w2lg, w2hp, w2lp);
  embed_kernel<<<416, 256, 0, stream>>>(ebg, ebp,
                                        w1hg, w1lg, gb1, w2hg, w2lg, gb2,
                                        w1hp, w1lp, pb1, w2hp, w2lp, pb2,
                                        g, p);
  loss_kernel<<<B_ / 4, 256, 0, stream>>>(g, p, pdil, pdcl);
  final_kernel<<<1, 256, 0, stream>>>(pdil, pdcl, out);
}